// Round 3
// baseline (2583.184 us; speedup 1.0000x reference)
//
#include <hip/hip_runtime.h>
#include <hip/hip_bf16.h>
#include <cmath>

// GMM E-step: N=131072, K=64, D=256.
// Round 3: A-fragments hoisted to registers (constant across components),
// 32x32x16 MFMA, B streamed through double-buffered LDS. Per-substep LDS
// traffic halved vs round 2 (B only); MFMA ceiling 2382 TF.

typedef unsigned short ushort_t;
typedef __attribute__((ext_vector_type(16))) float f32x16;
typedef __attribute__((ext_vector_type(8))) short bf16x8;

constexpr int N_ = 131072;
constexpr int K_ = 64;
constexpr int D_ = 256;
constexpr int BM = 128;                 // rows per block
constexpr int NBLK = N_ / BM;           // 1024 blocks
constexpr int BK = 64;                  // contraction substep
constexpr int NSUB = (K_ * D_) / BK;    // 256 total substeps

// ---------- helpers ----------
__device__ __forceinline__ ushort_t f2bf(float v) {
  unsigned u = __float_as_uint(v);
  u += 0x7FFFu + ((u >> 16) & 1u);  // RNE
  return (ushort_t)(u >> 16);
}

__device__ __forceinline__ void gld16(const ushort_t* g, ushort_t* l) {
  __builtin_amdgcn_global_load_lds(
      (const __attribute__((address_space(1))) unsigned int*)g,
      (__attribute__((address_space(3))) unsigned int*)l, 16, 0, 0);
}

// ---------- prep: X fp32 -> bf16 per-wave A-fragment image ----------
// e = ((T*2+wr)*32 + (ks*2+mt))*512 + l*8 + j   holds
//   bf16( X[T*128 + wr*64 + mt*32 + (l&31)][ks*16 + (l>>5)*8 + j] )
// (A-operand layout of mfma_f32_32x32x16_bf16: row=lane&31, k=(lane>>5)*8+j)
__global__ void prep_x(const float* __restrict__ X, ushort_t* __restrict__ Xb) {
  for (int e = blockIdx.x * blockDim.x + threadIdx.x; e < N_ * D_;
       e += gridDim.x * blockDim.x) {
    int j = e & 7;
    int l = (e >> 3) & 63;
    int mk = (e >> 9) & 31;   // ks*2+mt
    int wr = (e >> 14) & 1;
    int T = e >> 15;
    int mt = mk & 1, ks = mk >> 1;
    int row = T * 128 + wr * 64 + mt * 32 + (l & 31);
    int col = ks * 16 + (l >> 5) * 8 + j;
    Xb[e] = f2bf(X[(size_t)row * D_ + col]);
  }
}

// ---------- prep: P fp32 -> bf16 transposed+swizzled image ----------
// image element e = ((k*4+s)*256 + j)*64 + iq  holds
//   bf16( P[k][s*64 + (iq ^ ((j&7)<<3))][j] )
__global__ void prep_p(const float* __restrict__ P, ushort_t* __restrict__ Pb) {
  for (int e = blockIdx.x * blockDim.x + threadIdx.x; e < K_ * D_ * D_;
       e += gridDim.x * blockDim.x) {
    int iq = e & 63;
    int j = (e >> 6) & 255;
    int s = (e >> 14) & 3;
    int k = e >> 16;
    int il = iq ^ ((j & 7) << 3);
    Pb[e] = f2bf(P[((size_t)k * D_ + s * 64 + il) * D_ + j]);
  }
}

// ---------- prep: t[k][j] = sum_i mu[k][i]*P[k][i][j];  C[k] ----------
__global__ void prep_t(const float* __restrict__ P, const float* __restrict__ mu,
                       const float* __restrict__ w, float* __restrict__ t,
                       float* __restrict__ C) {
  int k = blockIdx.x, j = threadIdx.x;
  const float* Pk = P + (size_t)k * D_ * D_;
  const float* muk = mu + (size_t)k * D_;
  float acc = 0.f;
  for (int i = 0; i < D_; ++i) acc += muk[i] * Pk[(size_t)i * D_ + j];
  t[k * D_ + j] = acc;
  __shared__ float red[D_];
  red[j] = logf(Pk[(size_t)j * D_ + j]);
  __syncthreads();
  for (int s = 128; s > 0; s >>= 1) {
    if (j < s) red[j] += red[j + s];
    __syncthreads();
  }
  if (j == 0)
    C[k] = red[0] + logf(w[k]) - 0.5f * (float)D_ * logf(2.0f * (float)M_PI);
}

// ---------- main: A-in-registers fused GEMM + per-k sq-reduce ----------
__global__ __launch_bounds__(512, 2) void gmm_main(
    const ushort_t* __restrict__ Xb, const ushort_t* __restrict__ Pb,
    const float* __restrict__ tvec, const float* __restrict__ Cvec,
    float* __restrict__ wlp /* [N][K] */) {
  __shared__ __align__(16) ushort_t Bl[2][256 * 64];  // 64 KiB, P_k dbuf
  __shared__ float sqred[BM][4];

  const int tid = threadIdx.x;
  const int T = blockIdx.x;

  const int wid = tid >> 6, lane = tid & 63;
  const int wr = wid >> 2, wc = wid & 3;  // wave tile: 64 rows x 64 cols
  const int l31 = lane & 31, lg = lane >> 5;

  // ---- load A fragments for this wave: 32 x bf16x8 = 128 VGPRs ----
  const ushort_t* Ag = Xb + ((size_t)(T * 2 + wr) * 32) * 512;
  bf16x8 Areg[32];  // index ks*2+mt, all uses statically unrolled
#pragma unroll
  for (int f = 0; f < 32; ++f)
    Areg[f] = *(const bf16x8*)&Ag[(size_t)f * 512 + lane * 8];

  auto STAGE_B = [&](int buf, int step) {
    const ushort_t* gb = Pb + (size_t)step * (256 * 64);
#pragma unroll
    for (int it = 0; it < 4; ++it) {
      int off = (it * 512 + tid) * 8;  // 16B chunks, linear image
      gld16(gb + off, &Bl[buf][off]);
    }
  };

  // B-read addressing: col = wc*64 + n*32 + l31, kl = ki*16 + lg*8
  const int col0 = wc * 64 + l31;
  const int sw = (col0 & 7) << 3;  // same for col0 and col0+32

  STAGE_B(0, 0);
  asm volatile("s_waitcnt vmcnt(0)" ::: "memory");
  __syncthreads();

#pragma unroll 1
  for (int k = 0; k < K_; ++k) {
    // prefetch epilogue constants (consumed ~4000 cyc later)
    const float tv0 = tvec[k * D_ + col0];
    const float tv1 = tvec[k * D_ + col0 + 32];
    const float Ck = Cvec[k];

    f32x16 acc[2][2];
#pragma unroll
    for (int mt = 0; mt < 2; ++mt)
#pragma unroll
      for (int n = 0; n < 2; ++n)
#pragma unroll
        for (int r = 0; r < 16; ++r) acc[mt][n][r] = 0.f;

#pragma unroll
    for (int s = 0; s < 4; ++s) {
      const int buf = s & 1;
      const int g1 = k * 4 + s + 1;
      if (g1 < NSUB) STAGE_B(buf ^ 1, g1);
#pragma unroll
      for (int ki = 0; ki < 4; ++ki) {
        const int kl = ki * 16 + lg * 8;
        bf16x8 b0 = *(const bf16x8*)&Bl[buf][col0 * 64 + (kl ^ sw)];
        bf16x8 b1 = *(const bf16x8*)&Bl[buf][(col0 + 32) * 64 + (kl ^ sw)];
#pragma unroll
        for (int mt = 0; mt < 2; ++mt) {
          acc[mt][0] = __builtin_amdgcn_mfma_f32_32x32x16_bf16(
              Areg[(s * 4 + ki) * 2 + mt], b0, acc[mt][0], 0, 0, 0);
          acc[mt][1] = __builtin_amdgcn_mfma_f32_32x32x16_bf16(
              Areg[(s * 4 + ki) * 2 + mt], b1, acc[mt][1], 0, 0, 0);
        }
      }
      asm volatile("s_waitcnt vmcnt(0)" ::: "memory");
      __syncthreads();
    }

    // epilogue: sq over this wave's 64-col slice, reduce 32 lanes per half
#pragma unroll
    for (int mt = 0; mt < 2; ++mt) {
#pragma unroll
      for (int r = 0; r < 16; ++r) {
        float d0 = acc[mt][0][r] - tv0;
        float d1 = acc[mt][1][r] - tv1;
        float sfl = d0 * d0 + d1 * d1;
        sfl += __shfl_xor(sfl, 1, 64);
        sfl += __shfl_xor(sfl, 2, 64);
        sfl += __shfl_xor(sfl, 4, 64);
        sfl += __shfl_xor(sfl, 8, 64);
        sfl += __shfl_xor(sfl, 16, 64);
        if (l31 == 0) {
          int row = wr * 64 + mt * 32 + (r & 3) + 8 * (r >> 2) + 4 * lg;
          sqred[row][wc] = sfl;
        }
      }
    }
    __syncthreads();
    if (tid < BM) {
      float sq = sqred[tid][0] + sqred[tid][1] + sqred[tid][2] + sqred[tid][3];
      wlp[(size_t)(T * BM + tid) * K_ + k] = -0.5f * sq + Ck;
    }
    // next sqred write is >= 4 substep barriers away -> no extra barrier
  }
}

// ---------- LSE over k + write log_resp, per-block partial sums ----------
__global__ void lse_k(float* __restrict__ out, float* __restrict__ partial) {
  const int row = blockIdx.x * 256 + threadIdx.x;
  float* w = out + 1 + (size_t)row * K_;
  float v[K_];
  float mx = -1e30f;
#pragma unroll
  for (int j = 0; j < K_; ++j) {
    v[j] = w[j];
    mx = fmaxf(mx, v[j]);
  }
  float ssum = 0.f;
#pragma unroll
  for (int j = 0; j < K_; ++j) ssum += expf(v[j] - mx);
  float l = mx + logf(ssum);
#pragma unroll
  for (int j = 0; j < K_; ++j) w[j] = v[j] - l;
  __shared__ float red[256];
  red[threadIdx.x] = l;
  __syncthreads();
  for (int s = 128; s > 0; s >>= 1) {
    if (threadIdx.x < s) red[threadIdx.x] += red[threadIdx.x + s];
    __syncthreads();
  }
  if (threadIdx.x == 0) partial[blockIdx.x] = red[0];
}

__global__ void final_red(const float* __restrict__ partial,
                          float* __restrict__ out) {
  __shared__ float red[512];
  red[threadIdx.x] = partial[threadIdx.x];
  __syncthreads();
  for (int s = 256; s > 0; s >>= 1) {
    if (threadIdx.x < s) red[threadIdx.x] += red[threadIdx.x + s];
    __syncthreads();
  }
  if (threadIdx.x == 0) out[0] = red[0] * (1.0f / (float)N_);
}

extern "C" void kernel_launch(void* const* d_in, const int* in_sizes, int n_in,
                              void* d_out, int out_size, void* d_ws,
                              size_t ws_size, hipStream_t stream) {
  const float* X = (const float*)d_in[0];
  const float* w = (const float*)d_in[1];
  const float* mu = (const float*)d_in[2];
  const float* P = (const float*)d_in[3];
  float* out = (float*)d_out;
  char* ws = (char*)d_ws;

  // ws layout (bytes)
  ushort_t* Xb = (ushort_t*)ws;                         // 67,108,864
  ushort_t* Pb = (ushort_t*)(ws + 67108864);            // 8,388,608
  float* t = (float*)(ws + 75497472);                   // 65,536
  float* C = (float*)(ws + 75563008);                   // 256
  float* partial = (float*)(ws + 75563264);             // 2,048

  prep_x<<<2048, 256, 0, stream>>>(X, Xb);
  prep_p<<<2048, 256, 0, stream>>>(P, Pb);
  prep_t<<<K_, 256, 0, stream>>>(P, mu, w, t, C);
  gmm_main<<<NBLK, 512, 0, stream>>>(Xb, Pb, t, C, out + 1);
  lse_k<<<N_ / 256, 256, 0, stream>>>(out, partial);
  final_red<<<1, 512, 0, stream>>>(partial, out);
}